// Round 13
// baseline (184.835 us; speedup 1.0000x reference)
//
#include <hip/hip_runtime.h>
#include <hip/hip_bf16.h>

#define B_ 64
#define T_ 2048
#define E_ 256
#define U_ 256
#define O_ 32000
#define UE_ 512

typedef __attribute__((ext_vector_type(8))) short bf16x8;
typedef __attribute__((ext_vector_type(4))) float f32x4;

__device__ __forceinline__ unsigned short f2bf(float f){
  __hip_bfloat16 h = __float2bfloat16(f);
  return __builtin_bit_cast(unsigned short, h);
}
__device__ __forceinline__ unsigned pk2bf(float a, float b){
  return (unsigned)f2bf(a) | ((unsigned)f2bf(b) << 16);
}
__device__ __forceinline__ bf16x8 pack8(const float* v0, const float* v1){
  float4 x = *(const float4*)v0;
  float4 y = *(const float4*)v1;
  uint4 pk;
  pk.x = pk2bf(x.x, x.y); pk.y = pk2bf(x.z, x.w);
  pk.z = pk2bf(y.x, y.y); pk.w = pk2bf(y.z, y.w);
  return __builtin_bit_cast(bf16x8, pk);
}
__device__ __forceinline__ float ftanh(float x){
  float e = __expf(2.0f*x);
  return 1.0f - 2.0f/(e + 1.0f);
}
__device__ __forceinline__ float fsig(float x){
  return 1.0f/(1.0f + __expf(-x));
}

// ---------------- K0: fused pack (blocks 0..63) + stmpart (blocks 64..71) ----------------
__global__ __launch_bounds__(256)
void prep_kernel(const float* __restrict__ Wa, const float* __restrict__ stm,
                 unsigned short* __restrict__ bpack, float* __restrict__ sp){
  if (blockIdx.x < 64){
    int idx = blockIdx.x*256 + threadIdx.x;      // 16384 = 32 ktg * 512 n
    int n = idx & 511;
    int ktg = idx >> 9;
    int erow = ktg * 8;
    unsigned short o[8];
#pragma unroll
    for (int i = 0; i < 8; ++i)
      o[i] = f2bf(Wa[(256 + erow + i)*512 + n]);
    uint4 v;
    v.x = (unsigned)o[0] | ((unsigned)o[1] << 16);
    v.y = (unsigned)o[2] | ((unsigned)o[3] << 16);
    v.z = (unsigned)o[4] | ((unsigned)o[5] << 16);
    v.w = (unsigned)o[6] | ((unsigned)o[7] << 16);
    ((uint4*)bpack)[idx] = v;
  } else {
    int tid = threadIdx.x;
    int w = tid >> 6, l = tid & 63, c = l & 15, g = l >> 4;
    int n0 = (blockIdx.x - 64)*64 + w*16;        // 8 blocks -> 512 cols
    f32x4 zero = {0.f,0.f,0.f,0.f};
    f32x4 acc[4];
#pragma unroll
    for (int mt = 0; mt < 4; ++mt) acc[mt] = zero;
#pragma unroll
    for (int ks = 0; ks < 8; ++ks){
      int kg = ks*32 + 8*g;
      bf16x8 a[4];
#pragma unroll
      for (int mt = 0; mt < 4; ++mt){
        const float* ap = stm + (mt*16 + c)*256 + kg;
        a[mt] = pack8(ap, ap + 4);
      }
      const float* bpt = Wa + (size_t)kg*512 + n0 + c;
      float bv[8];
#pragma unroll
      for (int i = 0; i < 8; ++i) bv[i] = bpt[(size_t)i*512];
      uint4 pk;
      pk.x = pk2bf(bv[0], bv[1]); pk.y = pk2bf(bv[2], bv[3]);
      pk.z = pk2bf(bv[4], bv[5]); pk.w = pk2bf(bv[6], bv[7]);
      bf16x8 bfr = __builtin_bit_cast(bf16x8, pk);
#pragma unroll
      for (int mt = 0; mt < 4; ++mt)
        acc[mt] = __builtin_amdgcn_mfma_f32_16x16x32_bf16(a[mt], bfr, acc[mt], 0, 0, 0);
    }
#pragma unroll
    for (int mt = 0; mt < 4; ++mt)
#pragma unroll
      for (int r = 0; r < 4; ++r){
        int m = mt*16 + 4*g + r;
        sp[m*512 + n0 + c] = acc[mt][r];
      }
  }
}

// ---------------- K1 v13: flash et GEMM + piggybacked output-weight bf16 pack ----------------
// r12 core (91us, proven). Tail (doconv=1): each block converts 1500 weight octets
// (12000 fp32) of [Wo;Uo;Co] into MFMA-fragment-packed bf16 wpack, using et's idle HBM BW.
__global__ __launch_bounds__(512, 4)
void et_flash_kernel(const float* __restrict__ xseq, const unsigned short* __restrict__ bpack,
                     const float* __restrict__ va, const float* __restrict__ sp,
                     float* __restrict__ msbuf, float* __restrict__ uctxp,
                     const float* __restrict__ Wo2, const float* __restrict__ Uo2,
                     const float* __restrict__ Co2, unsigned short* __restrict__ wpack,
                     int doconv){
  __shared__ __align__(16) uint4 sA4[2048];   // 32KB
  __shared__ float sVa[512];
  __shared__ float sSp[512];
  __shared__ float sEt[8][64];
  __shared__ float sE[64];
  int tid = threadIdx.x;
  int w = tid >> 6, l = tid & 63, c = l & 15, g = l >> 4;
  int m0 = blockIdx.x * 64;
  int b  = m0 >> 11;

  // stage x tile (64 rows x 256 k) fp32 -> bf16 LDS (frag-contiguous, swizzled)
  const float4* x4 = (const float4*)xseq + (size_t)m0 * 64;
  uint2* sA2 = (uint2*)sA4;
#pragma unroll
  for (int i = 0; i < 8; ++i){
    int p = i*512 + tid;
    int row = p >> 6, kq = p & 63;
    float4 v = x4[row*64 + kq];
    uint2 u;
    u.x = pk2bf(v.x, v.y);
    u.y = pk2bf(v.z, v.w);
    int s = ((row>>4)*8 + (kq>>3))*64 + ((kq>>1)&3)*16 + (row&15);
    sA2[(s ^ ((s>>4)&7))*2 + (kq&1)] = u;
  }
  sVa[tid] = va[tid];
  sSp[tid] = sp[b*512 + tid];
  __syncthreads();

  f32x4 zero = {0.f, 0.f, 0.f, 0.f};
  f32x4 acc[4][4];       // [mt: n-frag][tc: t-frag] (swapped operands)
#pragma unroll
  for (int mt = 0; mt < 4; ++mt)
#pragma unroll
    for (int tc = 0; tc < 4; ++tc) acc[mt][tc] = zero;

  const bf16x8* bp = (const bf16x8*)bpack;
#pragma unroll
  for (int ks = 0; ks < 8; ++ks){
    bf16x8 aw[4], bx[4];
    int bbase = (ks*4 + g)*512 + w*64 + c;
#pragma unroll
    for (int mt = 0; mt < 4; ++mt)
      aw[mt] = bp[bbase + mt*16];           // W2 as A-operand
#pragma unroll
    for (int tc = 0; tc < 4; ++tc){
      int idx = (tc*8 + ks)*64 + l;
      bx[tc] = *(const bf16x8*)&sA4[idx ^ ((idx>>4)&7)];  // x as B-operand
    }
    __builtin_amdgcn_s_setprio(1);
#pragma unroll
    for (int mt = 0; mt < 4; ++mt)
#pragma unroll
      for (int tc = 0; tc < 4; ++tc)
        acc[mt][tc] = __builtin_amdgcn_mfma_f32_16x16x32_bf16(aw[mt], bx[tc], acc[mt][tc], 0, 0, 0);
    __builtin_amdgcn_s_setprio(0);
  }

  // epilogue: lane holds t-row = tc*16+c; n = w*64 + mt*16 + 4g + r
  float p[4] = {0.f, 0.f, 0.f, 0.f};
#pragma unroll
  for (int mt = 0; mt < 4; ++mt){
    int nb = w*64 + mt*16 + 4*g;
    float4 vav = *(const float4*)&sVa[nb];
    float4 spv = *(const float4*)&sSp[nb];
#pragma unroll
    for (int tc = 0; tc < 4; ++tc){
#pragma unroll
      for (int r = 0; r < 4; ++r){
        float vv = acc[mt][tc][r] + ((const float*)&spv)[r];
        p[tc] += ((const float*)&vav)[r] * ftanh(vv);
      }
    }
  }
#pragma unroll
  for (int tc = 0; tc < 4; ++tc){
    p[tc] += __shfl_xor(p[tc], 16, 64);
    p[tc] += __shfl_xor(p[tc], 32, 64);
  }
  if (l < 16){
#pragma unroll
    for (int tc = 0; tc < 4; ++tc)
      sEt[w][tc*16 + c] = p[tc];
  }
  __syncthreads();

  // ---- chunk softmax stats: m_c, s_c, sE[t] = exp(et_t - m_c) ----
  if (tid < 64){
    float e = 0.f;
#pragma unroll
    for (int ww = 0; ww < 8; ++ww) e += sEt[ww][tid];
    float m = e;
#pragma unroll
    for (int off = 1; off < 64; off <<= 1) m = fmaxf(m, __shfl_xor(m, off, 64));
    float ex = __expf(e - m);
    float s = ex;
#pragma unroll
    for (int off = 1; off < 64; off <<= 1) s += __shfl_xor(s, off, 64);
    sE[tid] = ex;
    if (tid == 0){
      msbuf[blockIdx.x*2]     = m;
      msbuf[blockIdx.x*2 + 1] = s;
    }
  }
  __syncthreads();

  // ---- uctx partial: thread (e = tid&255, th = tid>>8) sums 32 t-rows from LDS ----
  {
    int e = tid & 255, th = tid >> 8;
    int ks = e >> 5, gg = (e >> 3) & 3, ii = e & 7;
    const unsigned short* sU = (const unsigned short*)sA4;
    float a0 = 0.f;
#pragma unroll
    for (int tt = 0; tt < 32; ++tt){
      int t = th*32 + tt;
      int mt = t >> 4, cc = t & 15;
      int slt = (mt*8 + ks)*64 + gg*16 + cc;
      unsigned short hv = sU[(size_t)(slt ^ ((slt>>4)&7))*8 + ii];
      float xv = __builtin_bit_cast(float, ((unsigned)hv) << 16);
      a0 += sE[t] * xv;
    }
    uctxp[((size_t)blockIdx.x*2 + th)*256 + e] = a0;
  }

  // ---- piggybacked weight pack: octets q = bid*1500 + {tid, tid+512, tid+1024} ----
  // octet o (global, 0..96*32000): o = (ph*8+ks)*4+g fragment group; k = (o&31)*8 + i.
  if (doconv){
    for (int q0 = tid; q0 < 1500; q0 += 512){
      int q = blockIdx.x*1500 + q0;
      int o = q / 32000;
      int n = q - o*32000;
      int ph2 = o >> 5;
      int rowk = (o & 31) * 8;
      const float* srcw = (ph2 == 0) ? Wo2 : (ph2 == 1) ? Uo2 : Co2;
      const float* pw = srcw + (size_t)rowk*32000 + n;
      float wv0[8];
#pragma unroll
      for (int i = 0; i < 8; ++i) wv0[i] = pw[(size_t)i*32000];
      uint4 pkw;
      pkw.x = pk2bf(wv0[0], wv0[1]); pkw.y = pk2bf(wv0[2], wv0[3]);
      pkw.z = pk2bf(wv0[4], wv0[5]); pkw.w = pk2bf(wv0[6], wv0[7]);
      ((uint4*)wpack)[(size_t)o*32000 + n] = pkw;
    }
  }
}

// ---------------- K2: combine chunk (m,s,uctx) -> ctx; build X1bf ----------------
__global__ void ctx_x1_kernel(const float* __restrict__ msbuf, const float* __restrict__ uctxp,
                              const float* __restrict__ inputs, const float* __restrict__ stm,
                              unsigned short* __restrict__ X1bf){
  int b = blockIdx.x, e = threadIdx.x;   // 64 blocks x 256 threads
  float M = -INFINITY;
#pragma unroll 4
  for (int j = 0; j < 32; ++j) M = fmaxf(M, msbuf[(32*b + j)*2]);
  float S = 0.f;
  float acc = 0.f;
#pragma unroll 4
  for (int j = 0; j < 32; ++j){
    float wj = __expf(msbuf[(32*b + j)*2] - M);
    S += msbuf[(32*b + j)*2 + 1] * wj;
    size_t base = ((size_t)(32*b + j)*2)*256 + e;
    acc += (uctxp[base] + uctxp[base + 256]) * wj;
  }
  float ctx = acc / S;
  X1bf[b*768 + e]        = f2bf(inputs[b*256 + e]);
  X1bf[b*768 + 256 + e]  = f2bf(stm[b*256 + e]);
  X1bf[b*768 + 512 + e]  = f2bf(ctx);
}

// ---------------- K5a: gate preactivations r,z + p_ic via MFMA ----------------
__global__ __launch_bounds__(256)
void gates1_kernel(const unsigned short* __restrict__ X1bf, const float* __restrict__ stm,
                   const float* __restrict__ Wr, const float* __restrict__ Ur,
                   const float* __restrict__ Cr, const float* __restrict__ brr,
                   const float* __restrict__ Wz, const float* __restrict__ Uz,
                   const float* __restrict__ Cz, const float* __restrict__ bzz,
                   const float* __restrict__ Wp, const float* __restrict__ Cp,
                   const float* __restrict__ bpp,
                   float* __restrict__ rs, float* __restrict__ ztb, float* __restrict__ pic){
  int tid = threadIdx.x;
  int w = tid >> 6, l = tid & 63, c = l & 15, g = l >> 4;
  int n0 = blockIdx.x*64 + w*16;          // 12 blocks -> 768 cols
  int gate = n0 >> 8;
  int col0 = n0 & 255;
  const float* W0; const float* W1; const float* W2; const float* bias;
  if (gate == 0){ W0 = Wr; W1 = Ur; W2 = Cr; bias = brr; }
  else if (gate == 1){ W0 = Wz; W1 = Uz; W2 = Cz; bias = bzz; }
  else { W0 = Wp; W1 = nullptr; W2 = Cp; bias = bpp; }

  f32x4 zero = {0.f,0.f,0.f,0.f};
  f32x4 acc[4];
#pragma unroll
  for (int mt = 0; mt < 4; ++mt) acc[mt] = zero;

#pragma unroll
  for (int ph = 0; ph < 3; ++ph){
    const float* src = (ph == 0) ? W0 : (ph == 1) ? W1 : W2;
    if (src == nullptr) continue;
#pragma unroll
    for (int ks = 0; ks < 8; ++ks){
      int kg = ks*32 + 8*g;
      bf16x8 a[4];
#pragma unroll
      for (int mt = 0; mt < 4; ++mt)
        a[mt] = *(const bf16x8*)&X1bf[(mt*16 + c)*768 + ph*256 + kg];
      const float* bpt = src + (size_t)kg*256 + col0 + c;
      float bv[8];
#pragma unroll
      for (int i = 0; i < 8; ++i) bv[i] = bpt[(size_t)i*256];
      uint4 pk;
      pk.x = pk2bf(bv[0], bv[1]); pk.y = pk2bf(bv[2], bv[3]);
      pk.z = pk2bf(bv[4], bv[5]); pk.w = pk2bf(bv[6], bv[7]);
      bf16x8 bfr = __builtin_bit_cast(bf16x8, pk);
#pragma unroll
      for (int mt = 0; mt < 4; ++mt)
        acc[mt] = __builtin_amdgcn_mfma_f32_16x16x32_bf16(a[mt], bfr, acc[mt], 0, 0, 0);
    }
  }

  int n = col0 + c;
  float bi = bias[n];
#pragma unroll
  for (int mt = 0; mt < 4; ++mt)
#pragma unroll
    for (int r = 0; r < 4; ++r){
      int m = mt*16 + 4*g + r;
      float pre = acc[mt][r] + bi;
      if (gate == 0)      rs[m*256 + n]  = fsig(pre) * stm[m*256 + n];
      else if (gate == 1) ztb[m*256 + n] = fsig(pre);
      else                pic[m*256 + n] = pre;
    }
}

// ---------------- K5b: st = (1-z)*stm + z*tanh(pic + rs@Up) ----------------
__global__ __launch_bounds__(256)
void gates2_kernel(const float* __restrict__ rs, const float* __restrict__ Up,
                   const float* __restrict__ pic, const float* __restrict__ ztb,
                   const float* __restrict__ stm, float* __restrict__ stout){
  int tid = threadIdx.x;
  int w = tid >> 6, l = tid & 63, c = l & 15, g = l >> 4;
  int n0 = blockIdx.x*64 + w*16;          // 4 blocks -> 256 cols
  f32x4 zero = {0.f,0.f,0.f,0.f};
  f32x4 acc[4];
#pragma unroll
  for (int mt = 0; mt < 4; ++mt) acc[mt] = zero;
#pragma unroll
  for (int ks = 0; ks < 8; ++ks){
    int kg = ks*32 + 8*g;
    bf16x8 a[4];
#pragma unroll
    for (int mt = 0; mt < 4; ++mt){
      const float* ap = rs + (mt*16 + c)*256 + kg;
      a[mt] = pack8(ap, ap + 4);
    }
    const float* bpt = Up + (size_t)kg*256 + n0 + c;
    float bv[8];
#pragma unroll
    for (int i = 0; i < 8; ++i) bv[i] = bpt[(size_t)i*256];
    uint4 pk;
    pk.x = pk2bf(bv[0], bv[1]); pk.y = pk2bf(bv[2], bv[3]);
    pk.z = pk2bf(bv[4], bv[5]); pk.w = pk2bf(bv[6], bv[7]);
    bf16x8 bfr = __builtin_bit_cast(bf16x8, pk);
#pragma unroll
    for (int mt = 0; mt < 4; ++mt)
      acc[mt] = __builtin_amdgcn_mfma_f32_16x16x32_bf16(a[mt], bfr, acc[mt], 0, 0, 0);
  }
#pragma unroll
  for (int mt = 0; mt < 4; ++mt)
#pragma unroll
    for (int r = 0; r < 4; ++r){
      int m = mt*16 + 4*g + r;
      int o = m*256 + n0 + c;
      float ap = pic[o] + acc[mt][r];
      float z = ztb[o];
      stout[o] = (1.f - z)*stm[o] + z*ftanh(ap);
    }
}

// ---------------- K6a: logits from PACKED bf16 weights (k-split) + fused softmax partials ----------------
__global__ __launch_bounds__(512)
void logits_pk_kernel(const unsigned short* __restrict__ X1bf,
                      const unsigned short* __restrict__ wpack,
                      const float* __restrict__ boo,
                      float* __restrict__ outl, float* __restrict__ part2){
  __shared__ float sAcc[16][4][64];   // 16KB
  __shared__ float sMx[4][64];
  __shared__ float sSx[4][64];
  int tid = threadIdx.x;
  int w = tid >> 6, l = tid & 63, c = l & 15, g = l >> 4;
  int wc = w & 3;                     // col group
  int kh = w >> 2;                    // k-half (ks parity)
  int n0 = blockIdx.x*64 + wc*16;
  const bf16x8* wp = (const bf16x8*)wpack;
  f32x4 zero = {0.f,0.f,0.f,0.f};
  f32x4 acc[4];
#pragma unroll
  for (int mt = 0; mt < 4; ++mt) acc[mt] = zero;

#pragma unroll
  for (int ph = 0; ph < 3; ++ph){
#pragma unroll
    for (int kss = 0; kss < 4; ++kss){
      int ks = 2*kss + kh;
      int kg = ph*256 + ks*32 + 8*g;
      bf16x8 a[4];
#pragma unroll
      for (int mt = 0; mt < 4; ++mt)
        a[mt] = *(const bf16x8*)&X1bf[(mt*16 + c)*768 + kg];
      int o = (ph*8 + ks)*4 + g;
      bf16x8 bfr = wp[(size_t)o*32000 + n0 + c];
#pragma unroll
      for (int mt = 0; mt < 4; ++mt)
        acc[mt] = __builtin_amdgcn_mfma_f32_16x16x32_bf16(a[mt], bfr, acc[mt], 0, 0, 0);
    }
  }

  if (kh == 1){
#pragma unroll
    for (int mt = 0; mt < 4; ++mt)
#pragma unroll
      for (int r = 0; r < 4; ++r)
        sAcc[mt*4 + r][wc][l] = acc[mt][r];
  }
  __syncthreads();

  bool active = (kh == 0);
  float vv[4][4];
  if (active){
    float bias = boo[n0 + c];
#pragma unroll
    for (int mt = 0; mt < 4; ++mt)
#pragma unroll
      for (int r = 0; r < 4; ++r){
        int m = mt*16 + 4*g + r;
        vv[mt][r] = acc[mt][r] + sAcc[mt*4 + r][wc][l] + bias;
        outl[(size_t)m*32000 + n0 + c] = vv[mt][r];
      }
    float mx[4][4];
#pragma unroll
    for (int mt = 0; mt < 4; ++mt)
#pragma unroll
      for (int r = 0; r < 4; ++r) mx[mt][r] = vv[mt][r];
#pragma unroll
    for (int mask = 1; mask < 16; mask <<= 1)
#pragma unroll
      for (int mt = 0; mt < 4; ++mt)
#pragma unroll
        for (int r = 0; r < 4; ++r)
          mx[mt][r] = fmaxf(mx[mt][r], __shfl_xor(mx[mt][r], mask, 64));
    if (c == 0)
#pragma unroll
      for (int mt = 0; mt < 4; ++mt)
#pragma unroll
        for (int r = 0; r < 4; ++r)
          sMx[wc][mt*16 + 4*g + r] = mx[mt][r];
  }
  __syncthreads();
  if (active){
    float sx[4][4];
#pragma unroll
    for (int mt = 0; mt < 4; ++mt)
#pragma unroll
      for (int r = 0; r < 4; ++r){
        int row = mt*16 + 4*g + r;
        float M = fmaxf(fmaxf(sMx[0][row], sMx[1][row]), fmaxf(sMx[2][row], sMx[3][row]));
        sx[mt][r] = __expf(vv[mt][r] - M);
      }
#pragma unroll
    for (int mask = 1; mask < 16; mask <<= 1)
#pragma unroll
      for (int mt = 0; mt < 4; ++mt)
#pragma unroll
        for (int r = 0; r < 4; ++r)
          sx[mt][r] += __shfl_xor(sx[mt][r], mask, 64);
    if (c == 0)
#pragma unroll
      for (int mt = 0; mt < 4; ++mt)
#pragma unroll
        for (int r = 0; r < 4; ++r)
          sSx[wc][mt*16 + 4*g + r] = sx[mt][r];
  }
  __syncthreads();
  if (tid < 64){
    int row = tid;
    float M = fmaxf(fmaxf(sMx[0][row], sMx[1][row]), fmaxf(sMx[2][row], sMx[3][row]));
    float S = sSx[0][row] + sSx[1][row] + sSx[2][row] + sSx[3][row];
    part2[((size_t)blockIdx.x*64 + row)*2]     = M;
    part2[((size_t)blockIdx.x*64 + row)*2 + 1] = S;
  }
}

// ---------------- K6b: fallback logits from fp32 weights (r12 version) ----------------
__global__ __launch_bounds__(512)
void logits_mfma_kernel(const unsigned short* __restrict__ X1bf,
                        const float* __restrict__ Wo, const float* __restrict__ Uo,
                        const float* __restrict__ Co, const float* __restrict__ boo,
                        float* __restrict__ outl, float* __restrict__ part2){
  __shared__ float sAcc[16][4][64];
  __shared__ float sMx[4][64];
  __shared__ float sSx[4][64];
  int tid = threadIdx.x;
  int w = tid >> 6, l = tid & 63, c = l & 15, g = l >> 4;
  int wc = w & 3;
  int kh = w >> 2;
  int n0 = blockIdx.x*64 + wc*16;
  f32x4 zero = {0.f,0.f,0.f,0.f};
  f32x4 acc[4];
#pragma unroll
  for (int mt = 0; mt < 4; ++mt) acc[mt] = zero;

#pragma unroll
  for (int ph = 0; ph < 3; ++ph){
    const float* src = (ph == 0) ? Wo : (ph == 1) ? Uo : Co;
#pragma unroll
    for (int kss = 0; kss < 4; ++kss){
      int ks = 2*kss + kh;
      int kg = ph*256 + ks*32 + 8*g;
      bf16x8 a[4];
#pragma unroll
      for (int mt = 0; mt < 4; ++mt)
        a[mt] = *(const bf16x8*)&X1bf[(mt*16 + c)*768 + kg];
      const float* bpt = src + (size_t)(ks*32 + 8*g)*32000 + n0 + c;
      float bv[8];
#pragma unroll
      for (int i = 0; i < 8; ++i) bv[i] = bpt[(size_t)i*32000];
      uint4 pk;
      pk.x = pk2bf(bv[0], bv[1]);
      pk.y = pk2bf(bv[2], bv[3]);
      pk.z = pk2bf(bv[4], bv[5]);
      pk.w = pk2bf(bv[6], bv[7]);
      bf16x8 bfr = __builtin_bit_cast(bf16x8, pk);
#pragma unroll
      for (int mt = 0; mt < 4; ++mt)
        acc[mt] = __builtin_amdgcn_mfma_f32_16x16x32_bf16(a[mt], bfr, acc[mt], 0, 0, 0);
    }
  }

  if (kh == 1){
#pragma unroll
    for (int mt = 0; mt < 4; ++mt)
#pragma unroll
      for (int r = 0; r < 4; ++r)
        sAcc[mt*4 + r][wc][l] = acc[mt][r];
  }
  __syncthreads();

  bool active = (kh == 0);
  float vv[4][4];
  if (active){
    float bias = boo[n0 + c];
#pragma unroll
    for (int mt = 0; mt < 4; ++mt)
#pragma unroll
      for (int r = 0; r < 4; ++r){
        int m = mt*16 + 4*g + r;
        vv[mt][r] = acc[mt][r] + sAcc[mt*4 + r][wc][l] + bias;
        outl[(size_t)m*32000 + n0 + c] = vv[mt][r];
      }
    float mx[4][4];
#pragma unroll
    for (int mt = 0; mt < 4; ++mt)
#pragma unroll
      for (int r = 0; r < 4; ++r) mx[mt][r] = vv[mt][r];
#pragma unroll
    for (int mask = 1; mask < 16; mask <<= 1)
#pragma unroll
      for (int mt = 0; mt < 4; ++mt)
#pragma unroll
        for (int r = 0; r < 4; ++r)
          mx[mt][r] = fmaxf(mx[mt][r], __shfl_xor(mx[mt][r], mask, 64));
    if (c == 0)
#pragma unroll
      for (int mt = 0; mt < 4; ++mt)
#pragma unroll
        for (int r = 0; r < 4; ++r)
          sMx[wc][mt*16 + 4*g + r] = mx[mt][r];
  }
  __syncthreads();
  if (active){
    float sx[4][4];
#pragma unroll
    for (int mt = 0; mt < 4; ++mt)
#pragma unroll
      for (int r = 0; r < 4; ++r){
        int row = mt*16 + 4*g + r;
        float M = fmaxf(fmaxf(sMx[0][row], sMx[1][row]), fmaxf(sMx[2][row], sMx[3][row]));
        sx[mt][r] = __expf(vv[mt][r] - M);
      }
#pragma unroll
    for (int mask = 1; mask < 16; mask <<= 1)
#pragma unroll
      for (int mt = 0; mt < 4; ++mt)
#pragma unroll
        for (int r = 0; r < 4; ++r)
          sx[mt][r] += __shfl_xor(sx[mt][r], mask, 64);
    if (c == 0)
#pragma unroll
      for (int mt = 0; mt < 4; ++mt)
#pragma unroll
        for (int r = 0; r < 4; ++r)
          sSx[wc][mt*16 + 4*g + r] = sx[mt][r];
  }
  __syncthreads();
  if (tid < 64){
    int row = tid;
    float M = fmaxf(fmaxf(sMx[0][row], sMx[1][row]), fmaxf(sMx[2][row], sMx[3][row]));
    float S = sSx[0][row] + sSx[1][row] + sSx[2][row] + sSx[3][row];
    part2[((size_t)blockIdx.x*64 + row)*2]     = M;
    part2[((size_t)blockIdx.x*64 + row)*2 + 1] = S;
  }
}

// ---------------- K7a: combine 500 per-block partials -> fin[b] ----------------
__global__ void sm_comb_kernel(const float* __restrict__ part2, float* __restrict__ fin){
  __shared__ float red[8];
  __shared__ float red2[8];
  int b = blockIdx.x;            // 64 blocks
  int tid = threadIdx.x;         // 512 threads
  float M = -INFINITY, S = 0.f;
  if (tid < 500){
    M = part2[((size_t)tid*64 + b)*2];
    S = part2[((size_t)tid*64 + b)*2 + 1];
  }
  float m1 = M;
#pragma unroll
  for (int off = 1; off < 64; off <<= 1) m1 = fmaxf(m1, __shfl_xor(m1, off, 64));
  int wv = tid >> 6;
  if ((tid & 63) == 0) red[wv] = m1;
  __syncthreads();
  float Mg = red[0];
#pragma unroll
  for (int i = 1; i < 8; ++i) Mg = fmaxf(Mg, red[i]);
  float s1 = (tid < 500) ? S * __expf(M - Mg) : 0.f;
#pragma unroll
  for (int off = 1; off < 64; off <<= 1) s1 += __shfl_xor(s1, off, 64);
  if ((tid & 63) == 0) red2[wv] = s1;
  __syncthreads();
  if (tid == 0){
    float St = 0.f;
#pragma unroll
    for (int i = 0; i < 8; ++i) St += red2[i];
    fin[b*2] = Mg;
    fin[b*2 + 1] = St;
  }
}

// ---------------- K7b: normalize in place ----------------
__global__ void sm_norm_kernel(float* __restrict__ logits, const float* __restrict__ fin){
  int bid = blockIdx.x;
  int b = bid >> 3, ch = bid & 7;
  int base = b*32000 + ch*4000;
  int tid = threadIdx.x;
  float M = fin[2*b];
  float inv = 1.0f / fin[2*b + 1];
#pragma unroll
  for (int i = 0; i < 16; ++i){
    int idx = i*256 + tid;
    if (idx < 4000){
      int o = base + idx;
      logits[o] = __expf(logits[o] - M) * inv;
    }
  }
}

extern "C" void kernel_launch(void* const* d_in, const int* in_sizes, int n_in,
                              void* d_out, int out_size, void* d_ws, size_t ws_size,
                              hipStream_t stream) {
  const float* inputs = (const float*)d_in[0];
  const float* stm    = (const float*)d_in[1];
  const float* xseq   = (const float*)d_in[2];
  const float* Va     = (const float*)d_in[3];
  const float* Wa     = (const float*)d_in[4];
  const float* Wr = (const float*)d_in[5];
  const float* Ur = (const float*)d_in[6];
  const float* Cr = (const float*)d_in[7];
  const float* br = (const float*)d_in[8];
  const float* Wz = (const float*)d_in[9];
  const float* Uz = (const float*)d_in[10];
  const float* Cz = (const float*)d_in[11];
  const float* bz = (const float*)d_in[12];
  const float* Wp = (const float*)d_in[13];
  const float* Up = (const float*)d_in[14];
  const float* Cp = (const float*)d_in[15];
  const float* bp = (const float*)d_in[16];
  const float* Wo = (const float*)d_in[17];
  const float* Uo = (const float*)d_in[18];
  const float* Co = (const float*)d_in[19];
  const float* bo = (const float*)d_in[20];

  float* out   = (float*)d_out;            // [64][32000] softmax output
  float* stout = out + (size_t)B_*O_;      // [64][256] new state

  // ---- workspace map (float-slot offsets; part2/fin reuse dead et regions) ----
  float* wsf = (float*)d_ws;
  unsigned short* bpack = (unsigned short*)d_ws;           // floats [0, 65536)
  float* sp    = wsf + 65536;     // [65536,   98304)
  float* msbuf = wsf + 98304;     // [98304,   102400)  (dead after ctx_x1)
  float* uctxp = wsf + 102400;    // [102400,  1150976) (dead after ctx_x1)
  float* fin   = wsf + 98304;     // reuse msbuf region
  float* part2 = wsf + 102400;    // reuse uctxp region (500*64*2 floats)
  unsigned short* X1bf = (unsigned short*)(wsf + 1150976); // floats [1150976, 1175552)
  float* rs    = wsf + 1176576;   // [1176576, 1192960)
  float* ztb   = wsf + 1192960;   // [1192960, 1209344)
  float* pic   = wsf + 1209344;   // [1209344, 1225728)
  unsigned short* wpack = (unsigned short*)(wsf + 1225728); // ushort[24576000] = 49.2MB
  // total with wpack: 1225728*4 + 24576000*2 = 54,054,912 bytes
  int big = (ws_size >= (size_t)54054912) ? 1 : 0;

  prep_kernel<<<72, 256, 0, stream>>>(Wa, stm, bpack, sp);
  et_flash_kernel<<<2048, 512, 0, stream>>>(xseq, bpack, Va, sp, msbuf, uctxp,
                                            Wo, Uo, Co, wpack, big);
  ctx_x1_kernel<<<64, 256, 0, stream>>>(msbuf, uctxp, inputs, stm, X1bf);
  gates1_kernel<<<12, 256, 0, stream>>>(X1bf, stm, Wr, Ur, Cr, br,
                                        Wz, Uz, Cz, bz, Wp, Cp, bp,
                                        rs, ztb, pic);
  gates2_kernel<<<4, 256, 0, stream>>>(rs, Up, pic, ztb, stm, stout);
  if (big)
    logits_pk_kernel<<<500, 512, 0, stream>>>(X1bf, wpack, bo, out, part2);
  else
    logits_mfma_kernel<<<500, 512, 0, stream>>>(X1bf, Wo, Uo, Co, bo, out, part2);
  sm_comb_kernel<<<64, 512, 0, stream>>>(part2, fin);
  sm_norm_kernel<<<512, 256, 0, stream>>>(out, fin);
}

// Round 14
// 160.736 us; speedup vs baseline: 1.1499x; 1.1499x over previous
//
#include <hip/hip_runtime.h>
#include <hip/hip_bf16.h>

#define B_ 64
#define T_ 2048
#define E_ 256
#define U_ 256
#define O_ 32000
#define UE_ 512

typedef __attribute__((ext_vector_type(8))) short bf16x8;
typedef __attribute__((ext_vector_type(4))) float f32x4;

__device__ __forceinline__ unsigned short f2bf(float f){
  __hip_bfloat16 h = __float2bfloat16(f);
  return __builtin_bit_cast(unsigned short, h);
}
__device__ __forceinline__ unsigned pk2bf(float a, float b){
  return (unsigned)f2bf(a) | ((unsigned)f2bf(b) << 16);
}
__device__ __forceinline__ bf16x8 pack8(const float* v0, const float* v1){
  float4 x = *(const float4*)v0;
  float4 y = *(const float4*)v1;
  uint4 pk;
  pk.x = pk2bf(x.x, x.y); pk.y = pk2bf(x.z, x.w);
  pk.z = pk2bf(y.x, y.y); pk.w = pk2bf(y.z, y.w);
  return __builtin_bit_cast(bf16x8, pk);
}
__device__ __forceinline__ float ftanh(float x){
  float e = __expf(2.0f*x);
  return 1.0f - 2.0f/(e + 1.0f);
}
__device__ __forceinline__ float fsig(float x){
  return 1.0f/(1.0f + __expf(-x));
}

// ---------------- K0: fused pack (blocks 0..63) + stmpart (blocks 64..71) ----------------
__global__ __launch_bounds__(256)
void prep_kernel(const float* __restrict__ Wa, const float* __restrict__ stm,
                 unsigned short* __restrict__ bpack, float* __restrict__ sp){
  if (blockIdx.x < 64){
    int idx = blockIdx.x*256 + threadIdx.x;      // 16384 = 32 ktg * 512 n
    int n = idx & 511;
    int ktg = idx >> 9;
    int erow = ktg * 8;
    unsigned short o[8];
#pragma unroll
    for (int i = 0; i < 8; ++i)
      o[i] = f2bf(Wa[(256 + erow + i)*512 + n]);
    uint4 v;
    v.x = (unsigned)o[0] | ((unsigned)o[1] << 16);
    v.y = (unsigned)o[2] | ((unsigned)o[3] << 16);
    v.z = (unsigned)o[4] | ((unsigned)o[5] << 16);
    v.w = (unsigned)o[6] | ((unsigned)o[7] << 16);
    ((uint4*)bpack)[idx] = v;
  } else {
    int tid = threadIdx.x;
    int w = tid >> 6, l = tid & 63, c = l & 15, g = l >> 4;
    int n0 = (blockIdx.x - 64)*64 + w*16;        // 8 blocks -> 512 cols
    f32x4 zero = {0.f,0.f,0.f,0.f};
    f32x4 acc[4];
#pragma unroll
    for (int mt = 0; mt < 4; ++mt) acc[mt] = zero;
#pragma unroll
    for (int ks = 0; ks < 8; ++ks){
      int kg = ks*32 + 8*g;
      bf16x8 a[4];
#pragma unroll
      for (int mt = 0; mt < 4; ++mt){
        const float* ap = stm + (mt*16 + c)*256 + kg;
        a[mt] = pack8(ap, ap + 4);
      }
      const float* bpt = Wa + (size_t)kg*512 + n0 + c;
      float bv[8];
#pragma unroll
      for (int i = 0; i < 8; ++i) bv[i] = bpt[(size_t)i*512];
      uint4 pk;
      pk.x = pk2bf(bv[0], bv[1]); pk.y = pk2bf(bv[2], bv[3]);
      pk.z = pk2bf(bv[4], bv[5]); pk.w = pk2bf(bv[6], bv[7]);
      bf16x8 bfr = __builtin_bit_cast(bf16x8, pk);
#pragma unroll
      for (int mt = 0; mt < 4; ++mt)
        acc[mt] = __builtin_amdgcn_mfma_f32_16x16x32_bf16(a[mt], bfr, acc[mt], 0, 0, 0);
    }
#pragma unroll
    for (int mt = 0; mt < 4; ++mt)
#pragma unroll
      for (int r = 0; r < 4; ++r){
        int m = mt*16 + 4*g + r;
        sp[m*512 + n0 + c] = acc[mt][r];
      }
  }
}

// ---------------- K1: flash et GEMM (r12 core, proven 91us + fused online-softmax ctx) ----------------
__global__ __launch_bounds__(512, 4)
void et_flash_kernel(const float* __restrict__ xseq, const unsigned short* __restrict__ bpack,
                     const float* __restrict__ va, const float* __restrict__ sp,
                     float* __restrict__ msbuf, float* __restrict__ uctxp){
  __shared__ __align__(16) uint4 sA4[2048];   // 32KB
  __shared__ float sVa[512];
  __shared__ float sSp[512];
  __shared__ float sEt[8][64];
  __shared__ float sE[64];
  int tid = threadIdx.x;
  int w = tid >> 6, l = tid & 63, c = l & 15, g = l >> 4;
  int m0 = blockIdx.x * 64;
  int b  = m0 >> 11;

  // stage x tile (64 rows x 256 k) fp32 -> bf16 LDS (frag-contiguous, swizzled)
  const float4* x4 = (const float4*)xseq + (size_t)m0 * 64;
  uint2* sA2 = (uint2*)sA4;
#pragma unroll
  for (int i = 0; i < 8; ++i){
    int p = i*512 + tid;
    int row = p >> 6, kq = p & 63;
    float4 v = x4[row*64 + kq];
    uint2 u;
    u.x = pk2bf(v.x, v.y);
    u.y = pk2bf(v.z, v.w);
    int s = ((row>>4)*8 + (kq>>3))*64 + ((kq>>1)&3)*16 + (row&15);
    sA2[(s ^ ((s>>4)&7))*2 + (kq&1)] = u;
  }
  sVa[tid] = va[tid];
  sSp[tid] = sp[b*512 + tid];
  __syncthreads();

  f32x4 zero = {0.f, 0.f, 0.f, 0.f};
  f32x4 acc[4][4];       // [mt: n-frag][tc: t-frag] (swapped operands)
#pragma unroll
  for (int mt = 0; mt < 4; ++mt)
#pragma unroll
    for (int tc = 0; tc < 4; ++tc) acc[mt][tc] = zero;

  const bf16x8* bp = (const bf16x8*)bpack;
#pragma unroll
  for (int ks = 0; ks < 8; ++ks){
    bf16x8 aw[4], bx[4];
    int bbase = (ks*4 + g)*512 + w*64 + c;
#pragma unroll
    for (int mt = 0; mt < 4; ++mt)
      aw[mt] = bp[bbase + mt*16];           // W2 as A-operand
#pragma unroll
    for (int tc = 0; tc < 4; ++tc){
      int idx = (tc*8 + ks)*64 + l;
      bx[tc] = *(const bf16x8*)&sA4[idx ^ ((idx>>4)&7)];  // x as B-operand
    }
    __builtin_amdgcn_s_setprio(1);
#pragma unroll
    for (int mt = 0; mt < 4; ++mt)
#pragma unroll
      for (int tc = 0; tc < 4; ++tc)
        acc[mt][tc] = __builtin_amdgcn_mfma_f32_16x16x32_bf16(aw[mt], bx[tc], acc[mt][tc], 0, 0, 0);
    __builtin_amdgcn_s_setprio(0);
  }

  // epilogue: lane holds t-row = tc*16+c; n = w*64 + mt*16 + 4g + r
  float p[4] = {0.f, 0.f, 0.f, 0.f};
#pragma unroll
  for (int mt = 0; mt < 4; ++mt){
    int nb = w*64 + mt*16 + 4*g;
    float4 vav = *(const float4*)&sVa[nb];
    float4 spv = *(const float4*)&sSp[nb];
#pragma unroll
    for (int tc = 0; tc < 4; ++tc){
#pragma unroll
      for (int r = 0; r < 4; ++r){
        float vv = acc[mt][tc][r] + ((const float*)&spv)[r];
        p[tc] += ((const float*)&vav)[r] * ftanh(vv);
      }
    }
  }
#pragma unroll
  for (int tc = 0; tc < 4; ++tc){
    p[tc] += __shfl_xor(p[tc], 16, 64);
    p[tc] += __shfl_xor(p[tc], 32, 64);
  }
  if (l < 16){
#pragma unroll
    for (int tc = 0; tc < 4; ++tc)
      sEt[w][tc*16 + c] = p[tc];
  }
  __syncthreads();

  // ---- chunk softmax stats: m_c, s_c, sE[t] = exp(et_t - m_c) ----
  if (tid < 64){
    float e = 0.f;
#pragma unroll
    for (int ww = 0; ww < 8; ++ww) e += sEt[ww][tid];
    float m = e;
#pragma unroll
    for (int off = 1; off < 64; off <<= 1) m = fmaxf(m, __shfl_xor(m, off, 64));
    float ex = __expf(e - m);
    float s = ex;
#pragma unroll
    for (int off = 1; off < 64; off <<= 1) s += __shfl_xor(s, off, 64);
    sE[tid] = ex;
    if (tid == 0){
      msbuf[blockIdx.x*2]     = m;
      msbuf[blockIdx.x*2 + 1] = s;
    }
  }
  __syncthreads();

  // ---- uctx partial: thread (e = tid&255, th = tid>>8) sums 32 t-rows from LDS ----
  {
    int e = tid & 255, th = tid >> 8;
    int ks = e >> 5, gg = (e >> 3) & 3, ii = e & 7;
    const unsigned short* sU = (const unsigned short*)sA4;
    float a0 = 0.f;
#pragma unroll
    for (int tt = 0; tt < 32; ++tt){
      int t = th*32 + tt;
      int mt = t >> 4, cc = t & 15;
      int slt = (mt*8 + ks)*64 + gg*16 + cc;
      unsigned short hv = sU[(size_t)(slt ^ ((slt>>4)&7))*8 + ii];
      float xv = __builtin_bit_cast(float, ((unsigned)hv) << 16);
      a0 += sE[t] * xv;
    }
    uctxp[((size_t)blockIdx.x*2 + th)*256 + e] = a0;
  }
}

// ---------------- K2: combine chunk (m,s,uctx) -> ctx; build X1bf ----------------
__global__ void ctx_x1_kernel(const float* __restrict__ msbuf, const float* __restrict__ uctxp,
                              const float* __restrict__ inputs, const float* __restrict__ stm,
                              unsigned short* __restrict__ X1bf){
  int b = blockIdx.x, e = threadIdx.x;   // 64 blocks x 256 threads
  float M = -INFINITY;
#pragma unroll 4
  for (int j = 0; j < 32; ++j) M = fmaxf(M, msbuf[(32*b + j)*2]);
  float S = 0.f;
  float acc = 0.f;
#pragma unroll 4
  for (int j = 0; j < 32; ++j){
    float wj = __expf(msbuf[(32*b + j)*2] - M);
    S += msbuf[(32*b + j)*2 + 1] * wj;
    size_t base = ((size_t)(32*b + j)*2)*256 + e;
    acc += (uctxp[base] + uctxp[base + 256]) * wj;
  }
  float ctx = acc / S;
  X1bf[b*768 + e]        = f2bf(inputs[b*256 + e]);
  X1bf[b*768 + 256 + e]  = f2bf(stm[b*256 + e]);
  X1bf[b*768 + 512 + e]  = f2bf(ctx);
}

// ---------------- K5a: gate preactivations r,z + p_ic via MFMA ----------------
__global__ __launch_bounds__(256)
void gates1_kernel(const unsigned short* __restrict__ X1bf, const float* __restrict__ stm,
                   const float* __restrict__ Wr, const float* __restrict__ Ur,
                   const float* __restrict__ Cr, const float* __restrict__ brr,
                   const float* __restrict__ Wz, const float* __restrict__ Uz,
                   const float* __restrict__ Cz, const float* __restrict__ bzz,
                   const float* __restrict__ Wp, const float* __restrict__ Cp,
                   const float* __restrict__ bpp,
                   float* __restrict__ rs, float* __restrict__ ztb, float* __restrict__ pic){
  int tid = threadIdx.x;
  int w = tid >> 6, l = tid & 63, c = l & 15, g = l >> 4;
  int n0 = blockIdx.x*64 + w*16;          // 12 blocks -> 768 cols
  int gate = n0 >> 8;
  int col0 = n0 & 255;
  const float* W0; const float* W1; const float* W2; const float* bias;
  if (gate == 0){ W0 = Wr; W1 = Ur; W2 = Cr; bias = brr; }
  else if (gate == 1){ W0 = Wz; W1 = Uz; W2 = Cz; bias = bzz; }
  else { W0 = Wp; W1 = nullptr; W2 = Cp; bias = bpp; }

  f32x4 zero = {0.f,0.f,0.f,0.f};
  f32x4 acc[4];
#pragma unroll
  for (int mt = 0; mt < 4; ++mt) acc[mt] = zero;

#pragma unroll
  for (int ph = 0; ph < 3; ++ph){
    const float* src = (ph == 0) ? W0 : (ph == 1) ? W1 : W2;
    if (src == nullptr) continue;
#pragma unroll
    for (int ks = 0; ks < 8; ++ks){
      int kg = ks*32 + 8*g;
      bf16x8 a[4];
#pragma unroll
      for (int mt = 0; mt < 4; ++mt)
        a[mt] = *(const bf16x8*)&X1bf[(mt*16 + c)*768 + ph*256 + kg];
      const float* bpt = src + (size_t)kg*256 + col0 + c;
      float bv[8];
#pragma unroll
      for (int i = 0; i < 8; ++i) bv[i] = bpt[(size_t)i*256];
      uint4 pk;
      pk.x = pk2bf(bv[0], bv[1]); pk.y = pk2bf(bv[2], bv[3]);
      pk.z = pk2bf(bv[4], bv[5]); pk.w = pk2bf(bv[6], bv[7]);
      bf16x8 bfr = __builtin_bit_cast(bf16x8, pk);
#pragma unroll
      for (int mt = 0; mt < 4; ++mt)
        acc[mt] = __builtin_amdgcn_mfma_f32_16x16x32_bf16(a[mt], bfr, acc[mt], 0, 0, 0);
    }
  }

  int n = col0 + c;
  float bi = bias[n];
#pragma unroll
  for (int mt = 0; mt < 4; ++mt)
#pragma unroll
    for (int r = 0; r < 4; ++r){
      int m = mt*16 + 4*g + r;
      float pre = acc[mt][r] + bi;
      if (gate == 0)      rs[m*256 + n]  = fsig(pre) * stm[m*256 + n];
      else if (gate == 1) ztb[m*256 + n] = fsig(pre);
      else                pic[m*256 + n] = pre;
    }
}

// ---------------- K5b: st = (1-z)*stm + z*tanh(pic + rs@Up) ----------------
__global__ __launch_bounds__(256)
void gates2_kernel(const float* __restrict__ rs, const float* __restrict__ Up,
                   const float* __restrict__ pic, const float* __restrict__ ztb,
                   const float* __restrict__ stm, float* __restrict__ stout){
  int tid = threadIdx.x;
  int w = tid >> 6, l = tid & 63, c = l & 15, g = l >> 4;
  int n0 = blockIdx.x*64 + w*16;          // 4 blocks -> 256 cols
  f32x4 zero = {0.f,0.f,0.f,0.f};
  f32x4 acc[4];
#pragma unroll
  for (int mt = 0; mt < 4; ++mt) acc[mt] = zero;
#pragma unroll
  for (int ks = 0; ks < 8; ++ks){
    int kg = ks*32 + 8*g;
    bf16x8 a[4];
#pragma unroll
    for (int mt = 0; mt < 4; ++mt){
      const float* ap = rs + (mt*16 + c)*256 + kg;
      a[mt] = pack8(ap, ap + 4);
    }
    const float* bpt = Up + (size_t)kg*256 + n0 + c;
    float bv[8];
#pragma unroll
    for (int i = 0; i < 8; ++i) bv[i] = bpt[(size_t)i*256];
    uint4 pk;
    pk.x = pk2bf(bv[0], bv[1]); pk.y = pk2bf(bv[2], bv[3]);
    pk.z = pk2bf(bv[4], bv[5]); pk.w = pk2bf(bv[6], bv[7]);
    bf16x8 bfr = __builtin_bit_cast(bf16x8, pk);
#pragma unroll
    for (int mt = 0; mt < 4; ++mt)
      acc[mt] = __builtin_amdgcn_mfma_f32_16x16x32_bf16(a[mt], bfr, acc[mt], 0, 0, 0);
  }
#pragma unroll
  for (int mt = 0; mt < 4; ++mt)
#pragma unroll
    for (int r = 0; r < 4; ++r){
      int m = mt*16 + 4*g + r;
      int o = m*256 + n0 + c;
      float ap = pic[o] + acc[mt][r];
      float z = ztb[o];
      stout[o] = (1.f - z)*stm[o] + z*ftanh(ap);
    }
}

// ---------------- K6: logits via MFMA (k-split) + fused per-block softmax partials ----------------
__global__ __launch_bounds__(512)
void logits_mfma_kernel(const unsigned short* __restrict__ X1bf,
                        const float* __restrict__ Wo, const float* __restrict__ Uo,
                        const float* __restrict__ Co, const float* __restrict__ boo,
                        float* __restrict__ outl, float* __restrict__ part2){
  __shared__ float sAcc[16][4][64];   // 16KB
  __shared__ float sMx[4][64];
  __shared__ float sSx[4][64];
  int tid = threadIdx.x;
  int w = tid >> 6, l = tid & 63, c = l & 15, g = l >> 4;
  int wc = w & 3;                     // col group
  int kh = w >> 2;                    // k-half (ks parity)
  int n0 = blockIdx.x*64 + wc*16;
  f32x4 zero = {0.f,0.f,0.f,0.f};
  f32x4 acc[4];
#pragma unroll
  for (int mt = 0; mt < 4; ++mt) acc[mt] = zero;

#pragma unroll
  for (int ph = 0; ph < 3; ++ph){
    const float* src = (ph == 0) ? Wo : (ph == 1) ? Uo : Co;
#pragma unroll
    for (int kss = 0; kss < 4; ++kss){
      int ks = 2*kss + kh;
      int kg = ph*256 + ks*32 + 8*g;
      bf16x8 a[4];
#pragma unroll
      for (int mt = 0; mt < 4; ++mt)
        a[mt] = *(const bf16x8*)&X1bf[(mt*16 + c)*768 + kg];
      const float* bpt = src + (size_t)(ks*32 + 8*g)*32000 + n0 + c;
      float bv[8];
#pragma unroll
      for (int i = 0; i < 8; ++i) bv[i] = bpt[(size_t)i*32000];
      uint4 pk;
      pk.x = pk2bf(bv[0], bv[1]);
      pk.y = pk2bf(bv[2], bv[3]);
      pk.z = pk2bf(bv[4], bv[5]);
      pk.w = pk2bf(bv[6], bv[7]);
      bf16x8 bfr = __builtin_bit_cast(bf16x8, pk);
#pragma unroll
      for (int mt = 0; mt < 4; ++mt)
        acc[mt] = __builtin_amdgcn_mfma_f32_16x16x32_bf16(a[mt], bfr, acc[mt], 0, 0, 0);
    }
  }

  if (kh == 1){
#pragma unroll
    for (int mt = 0; mt < 4; ++mt)
#pragma unroll
      for (int r = 0; r < 4; ++r)
        sAcc[mt*4 + r][wc][l] = acc[mt][r];
  }
  __syncthreads();

  bool active = (kh == 0);
  float vv[4][4];
  if (active){
    float bias = boo[n0 + c];
#pragma unroll
    for (int mt = 0; mt < 4; ++mt)
#pragma unroll
      for (int r = 0; r < 4; ++r){
        int m = mt*16 + 4*g + r;
        vv[mt][r] = acc[mt][r] + sAcc[mt*4 + r][wc][l] + bias;
        outl[(size_t)m*32000 + n0 + c] = vv[mt][r];
      }
    float mx[4][4];
#pragma unroll
    for (int mt = 0; mt < 4; ++mt)
#pragma unroll
      for (int r = 0; r < 4; ++r) mx[mt][r] = vv[mt][r];
#pragma unroll
    for (int mask = 1; mask < 16; mask <<= 1)
#pragma unroll
      for (int mt = 0; mt < 4; ++mt)
#pragma unroll
        for (int r = 0; r < 4; ++r)
          mx[mt][r] = fmaxf(mx[mt][r], __shfl_xor(mx[mt][r], mask, 64));
    if (c == 0)
#pragma unroll
      for (int mt = 0; mt < 4; ++mt)
#pragma unroll
        for (int r = 0; r < 4; ++r)
          sMx[wc][mt*16 + 4*g + r] = mx[mt][r];
  }
  __syncthreads();
  if (active){
    float sx[4][4];
#pragma unroll
    for (int mt = 0; mt < 4; ++mt)
#pragma unroll
      for (int r = 0; r < 4; ++r){
        int row = mt*16 + 4*g + r;
        float M = fmaxf(fmaxf(sMx[0][row], sMx[1][row]), fmaxf(sMx[2][row], sMx[3][row]));
        sx[mt][r] = __expf(vv[mt][r] - M);
      }
#pragma unroll
    for (int mask = 1; mask < 16; mask <<= 1)
#pragma unroll
      for (int mt = 0; mt < 4; ++mt)
#pragma unroll
        for (int r = 0; r < 4; ++r)
          sx[mt][r] += __shfl_xor(sx[mt][r], mask, 64);
    if (c == 0)
#pragma unroll
      for (int mt = 0; mt < 4; ++mt)
#pragma unroll
        for (int r = 0; r < 4; ++r)
          sSx[wc][mt*16 + 4*g + r] = sx[mt][r];
  }
  __syncthreads();
  if (tid < 64){
    int row = tid;
    float M = fmaxf(fmaxf(sMx[0][row], sMx[1][row]), fmaxf(sMx[2][row], sMx[3][row]));
    float S = sSx[0][row] + sSx[1][row] + sSx[2][row] + sSx[3][row];
    part2[((size_t)blockIdx.x*64 + row)*2]     = M;
    part2[((size_t)blockIdx.x*64 + row)*2 + 1] = S;
  }
}

// ---------------- K7: normalize in place (global combine fused in, 512 threads) ----------------
__global__ __launch_bounds__(512)
void sm_norm_kernel(float* __restrict__ logits, const float* __restrict__ part2){
  __shared__ float red[8];
  __shared__ float red2[8];
  __shared__ float sMS[2];
  int bid = blockIdx.x;
  int b = bid >> 3, ch = bid & 7;
  int base = b*32000 + ch*4000;
  int tid = threadIdx.x;

  // cooperative combine of the 500 per-logits-block partials for this b
  float M = -INFINITY, S = 0.f;
  if (tid < 500){
    M = part2[((size_t)tid*64 + b)*2];
    S = part2[((size_t)tid*64 + b)*2 + 1];
  }
  float m1 = M;
#pragma unroll
  for (int off = 1; off < 64; off <<= 1) m1 = fmaxf(m1, __shfl_xor(m1, off, 64));
  int wv = tid >> 6;
  if ((tid & 63) == 0) red[wv] = m1;
  __syncthreads();
  float Mg = red[0];
#pragma unroll
  for (int i = 1; i < 8; ++i) Mg = fmaxf(Mg, red[i]);
  float s1 = (tid < 500) ? S * __expf(M - Mg) : 0.f;
#pragma unroll
  for (int off = 1; off < 64; off <<= 1) s1 += __shfl_xor(s1, off, 64);
  if ((tid & 63) == 0) red2[wv] = s1;
  __syncthreads();
  if (tid == 0){
    float St = 0.f;
#pragma unroll
    for (int i = 0; i < 8; ++i) St += red2[i];
    sMS[0] = Mg;
    sMS[1] = 1.0f / St;
  }
  __syncthreads();
  float Mf = sMS[0];
  float inv = sMS[1];
#pragma unroll
  for (int i = 0; i < 8; ++i){
    int idx = i*512 + tid;
    if (idx < 4000){
      int o = base + idx;
      logits[o] = __expf(logits[o] - Mf) * inv;
    }
  }
}

extern "C" void kernel_launch(void* const* d_in, const int* in_sizes, int n_in,
                              void* d_out, int out_size, void* d_ws, size_t ws_size,
                              hipStream_t stream) {
  const float* inputs = (const float*)d_in[0];
  const float* stm    = (const float*)d_in[1];
  const float* xseq   = (const float*)d_in[2];
  const float* Va     = (const float*)d_in[3];
  const float* Wa     = (const float*)d_in[4];
  const float* Wr = (const float*)d_in[5];
  const float* Ur = (const float*)d_in[6];
  const float* Cr = (const float*)d_in[7];
  const float* br = (const float*)d_in[8];
  const float* Wz = (const float*)d_in[9];
  const float* Uz = (const float*)d_in[10];
  const float* Cz = (const float*)d_in[11];
  const float* bz = (const float*)d_in[12];
  const float* Wp = (const float*)d_in[13];
  const float* Up = (const float*)d_in[14];
  const float* Cp = (const float*)d_in[15];
  const float* bp = (const float*)d_in[16];
  const float* Wo = (const float*)d_in[17];
  const float* Uo = (const float*)d_in[18];
  const float* Co = (const float*)d_in[19];
  const float* bo = (const float*)d_in[20];

  float* out   = (float*)d_out;            // [64][32000] softmax output
  float* stout = out + (size_t)B_*O_;      // [64][256] new state

  // ---- workspace map (float-slot offsets; part2 reuses dead et region) ----
  float* wsf = (float*)d_ws;
  unsigned short* bpack = (unsigned short*)d_ws;           // floats [0, 65536)
  float* sp    = wsf + 65536;     // [65536,   98304)
  float* msbuf = wsf + 98304;     // [98304,   102400)  (dead after ctx_x1)
  float* uctxp = wsf + 102400;    // [102400,  1150976) (dead after ctx_x1)
  float* part2 = wsf + 102400;    // reuse uctxp region (500*64*2 floats)
  unsigned short* X1bf = (unsigned short*)(wsf + 1150976); // floats [1150976, 1175552)
  float* rs    = wsf + 1176576;   // [1176576, 1192960)
  float* ztb   = wsf + 1192960;   // [1192960, 1209344)
  float* pic   = wsf + 1209344;   // [1209344, 1225728)

  prep_kernel<<<72, 256, 0, stream>>>(Wa, stm, bpack, sp);
  et_flash_kernel<<<2048, 512, 0, stream>>>(xseq, bpack, Va, sp, msbuf, uctxp);
  ctx_x1_kernel<<<64, 256, 0, stream>>>(msbuf, uctxp, inputs, stm, X1bf);
  gates1_kernel<<<12, 256, 0, stream>>>(X1bf, stm, Wr, Ur, Cr, br,
                                        Wz, Uz, Cz, bz, Wp, Cp, bp,
                                        rs, ztb, pic);
  gates2_kernel<<<4, 256, 0, stream>>>(rs, Up, pic, ztb, stm, stout);
  logits_mfma_kernel<<<500, 512, 0, stream>>>(X1bf, Wo, Uo, Co, bo, out, part2);
  sm_norm_kernel<<<512, 512, 0, stream>>>(out, part2);
}